// Round 14
// baseline (5640.533 us; speedup 1.0000x reference)
//
#include <hip/hip_runtime.h>
#include <hip/hip_bf16.h>
#include <stdint.h>

#define B_  256
#define T_  512
#define H_  1024
#define BH  (B_ * H_)

typedef float  f32x4  __attribute__((ext_vector_type(4)));
typedef float  f32x16 __attribute__((ext_vector_type(16)));
typedef __bf16 bf16x8 __attribute__((ext_vector_type(8)));

// packed f32x2 -> bf16x2 (low = a, high = b), RNE in HW
__device__ inline uint32_t cvtpk(float a, float b) {
  uint32_t r;
  asm("v_cvt_pk_bf16_f32 %0, %1, %2" : "=v"(r) : "v"(a), "v"(b));
  return r;
}
__device__ inline bf16x8 as_bf8(uint4 u) {
  union { uint4 a; bf16x8 b; } v; v.a = u; return v.b;
}
// 8 fp32 (two uint4-bitcast float4s) -> bf16x8, order-preserving
__device__ inline bf16x8 cvt8(uint4 lo, uint4 hi) {
  union { uint4 u; float4 v; } a, b;
  a.u = lo; b.u = hi;
  uint4 w;
  w.x = cvtpk(a.v.x, a.v.y); w.y = cvtpk(a.v.z, a.v.w);
  w.z = cvtpk(b.v.x, b.v.y); w.w = cvtpk(b.v.z, b.v.w);
  return as_bf8(w);
}
// plain cached 16B load, UNTRACKED (caller waits vmcnt). h-freshness guaranteed
// by 8-deep buffer rotation + agent-acquire fence every 8 steps (r12/r13-proven).
__device__ inline uint4 ld16_pl(const void* p) {
  uint4 r;
  asm volatile("global_load_dwordx4 %0, %1, off" : "=&v"(r) : "v"(p));
  return r;
}
// device-scope 8B store (to coherence point; visible to all XCDs)
__device__ inline void st8_coh(ushort* p, uint2 v) {
  asm volatile("global_store_dwordx2 %0, %1, off sc1" :: "v"(p), "v"(v) : "memory");
}
__device__ inline float tanh_fast(float x) {
  float xc = fminf(fmaxf(x, -15.f), 15.f);
  float e  = __expf(2.f * xc);
  return (e - 1.f) * __builtin_amdgcn_rcpf(e + 1.f);
}

// ------------------------------------------- fused persistent RNN (x + scan)
// r13 structure + protocol (256 wgs XCD-aligned rt=bid&7, wave = K-quarter,
// 32x32x16 MFMA, repacked epilogue, sc1 h-stores, flag/poll, cached h-loads,
// 8-buffer rotation, fence/8). r14 delta: x_proj FUSED into the step loop.
// Per iteration s: (1) x-part — xs[:,s,:]@Wx^T MFMAs, NO peer dependency,
// overlaps the poll; (2) poll h(s); (3) h-part accumulates into same acc;
// (4) 2-phase Psm reduce; h_{s+1} = tanh(acc + bias). xproj kernel, xp
// buffer, and its 512 MB of xp traffic are eliminated.
__global__ __launch_bounds__(256) void rnn_scan(const float* __restrict__ W,
                                                const float* __restrict__ xs,
                                                const float* __restrict__ bias,
                                                ushort* __restrict__ hb,
                                                float* __restrict__ out,
                                                int* __restrict__ flags) {
  __shared__ ushort Wxs[32 * 1024];          // 64 KB: Wx cols [ct*32, +32)
  __shared__ ushort Whs[32 * 1024];          // 64 KB: Wh cols [ct*32, +32)
  __shared__ float  Psm[2][32][68];          // 17 KB partials (2-phase reduce)
  const int bid = blockIdx.x, tid = threadIdx.x;
  const int rt = bid & 7, ct = bid >> 3;     // XCD-aligned (r13-proven)
  const int lane = tid & 63;
  const int kq = tid >> 6;                   // wave: K-quarter [kq*256, +256)
  const int l31 = lane & 31, l5 = lane >> 5;
  const int rbase = rt * 32;

  // ---- one-time stage: Wx AND Wh cols -> bf16 LDS, 16B-granule swizzle
  {
    const int c  = tid >> 3;                 // 0..31  (local col)
    const int qb = (tid & 7) * 16;           // 16 x 16B chunks per thread
    const float* srcx = W + (size_t)(ct * 32 + c) * 2048;        // Wx
    const float* srch = srcx + 1024;                             // Wh
    char* dstx = (char*)Wxs + c * 2048;
    char* dsth = (char*)Whs + c * 2048;
    const int sw = (c & 7) << 4;
#pragma unroll
    for (int q = qb; q < qb + 16; ++q) {
      float4 f0 = *(const float4*)(srcx + q * 8);
      float4 f1 = *(const float4*)(srcx + q * 8 + 4);
      uint4 w;
      w.x = cvtpk(f0.x, f0.y); w.y = cvtpk(f0.z, f0.w);
      w.z = cvtpk(f1.x, f1.y); w.w = cvtpk(f1.z, f1.w);
      *(uint4*)(dstx + ((q * 16) ^ sw)) = w;
      f0 = *(const float4*)(srch + q * 8);
      f1 = *(const float4*)(srch + q * 8 + 4);
      w.x = cvtpk(f0.x, f0.y); w.y = cvtpk(f0.z, f0.w);
      w.z = cvtpk(f1.x, f1.y); w.w = cvtpk(f1.z, f1.w);
      *(uint4*)(dsth + ((q * 16) ^ sw)) = w;
    }
  }
  __syncthreads();

  // B frag (r8-proven): col = ct*32 + l31, k = kq*256 + c*16 + l5*8
  const int swz = (l31 & 7) << 4;
  const char* bpx = (char*)Wxs + l31 * 2048 + kq * 512;
  const char* bph = (char*)Whs + l31 * 2048 + kq * 512;
  // C/D rows (m74/m101): row = (r&3) + 8*(r>>2) + 4*l5, col = l31
  int crow[16];
#pragma unroll
  for (int r = 0; r < 16; ++r) crow[r] = (r & 3) + 8 * (r >> 2) + 4 * l5;

  // repack indexing: thread -> (row, 4 cols)
  const int prow = tid >> 3, pcg = tid & 7;
  const int gr = rbase + prow;
  const int gc = ct * 32 + pcg * 4;
  const f32x4 bias4 = *(const f32x4*)(bias + gc);

  // per-wave A-row bases
  const float* xbase = xs + (size_t)(rbase + l31) * 512 * 1024 + kq * 256 + l5 * 8;

  for (int s = 0; s < T_; ++s) {
    // ================= x-part: xs[:,s,:] @ Wx^T — no peer dependency =======
    const float* xrow = xbase + (size_t)s * 1024;
    uint4 XF[32];
#pragma unroll
    for (int c = 0; c < 16; ++c) {
      XF[2 * c]     = ld16_pl(xrow + c * 16);
      XF[2 * c + 1] = ld16_pl(xrow + c * 16 + 4);
    }
    asm volatile("s_waitcnt vmcnt(16)" ::: "memory");  // chunks 0..7 ready
    __builtin_amdgcn_sched_barrier(0);

    f32x16 acc;
#pragma unroll
    for (int i = 0; i < 16; ++i) acc[i] = 0.f;

#pragma unroll
    for (int c = 0; c < 8; ++c) {
      const int off = ((c * 32) | (l5 * 16)) ^ swz;
      acc = __builtin_amdgcn_mfma_f32_32x32x16_bf16(cvt8(XF[2 * c], XF[2 * c + 1]),
                                                    *(const bf16x8*)(bpx + off), acc, 0, 0, 0);
    }
    asm volatile("s_waitcnt vmcnt(0)" ::: "memory");
    __builtin_amdgcn_sched_barrier(0);
#pragma unroll
    for (int c = 8; c < 16; ++c) {
      const int off = ((c * 32) | (l5 * 16)) ^ swz;
      acc = __builtin_amdgcn_mfma_f32_32x32x16_bf16(cvt8(XF[2 * c], XF[2 * c + 1]),
                                                    *(const bf16x8*)(bpx + off), acc, 0, 0, 0);
    }

    // ================= poll: h(s) ready (skip at s == 0; h0 == 0) ==========
    if (s > 0) {
      if (tid < 32) {
        while (__hip_atomic_load(flags + (tid * 8 + rt) * 16, __ATOMIC_RELAXED,
                                 __HIP_MEMORY_SCOPE_AGENT) < s) {}
      }
      __syncthreads();
      // periodic invalidate before h-reads of a reused buffer generation
      // (every 8 steps; s==1 also clears cross-replay staleness)
      if ((s & 7) == 1) __builtin_amdgcn_fence(__ATOMIC_ACQUIRE, "agent");

      // =============== h-part: h(s) @ Wh^T into the same acc ===============
      const ushort* hprev = hb + (size_t)(s & 7) * BH;
      const ushort* arow  = hprev + (size_t)(rbase + l31) * H_ + kq * 256 + l5 * 8;
      uint4 A[16];
#pragma unroll
      for (int c = 0; c < 16; ++c) A[c] = ld16_pl(arow + c * 16);

      asm volatile("s_waitcnt vmcnt(8)" ::: "memory");
      __builtin_amdgcn_sched_barrier(0);
#pragma unroll
      for (int c = 0; c < 8; ++c) {
        const int off = ((c * 32) | (l5 * 16)) ^ swz;
        acc = __builtin_amdgcn_mfma_f32_32x32x16_bf16(as_bf8(A[c]),
                                                      *(const bf16x8*)(bph + off), acc, 0, 0, 0);
      }
      asm volatile("s_waitcnt vmcnt(0)" ::: "memory");
      __builtin_amdgcn_sched_barrier(0);
#pragma unroll
      for (int c = 8; c < 16; ++c) {
        const int off = ((c * 32) | (l5 * 16)) ^ swz;
        acc = __builtin_amdgcn_mfma_f32_32x32x16_bf16(as_bf8(A[c]),
                                                      *(const bf16x8*)(bph + off), acc, 0, 0, 0);
      }
    }

    // ================= 2-phase deterministic K-reduce through Psm ==========
    if (kq < 2) {
#pragma unroll
      for (int r = 0; r < 16; ++r) Psm[kq][crow[r]][l31] = acc[r];
    }
    __syncthreads();
    if (kq >= 2) {
#pragma unroll
      for (int r = 0; r < 16; ++r) Psm[kq - 2][crow[r]][l31] += acc[r];
    }
    __syncthreads();

    f32x4 s4 = *(const f32x4*)&Psm[0][prow][pcg * 4]
             + *(const f32x4*)&Psm[1][prow][pcg * 4] + bias4;

    if (s < T_ - 1) {
      float v0 = tanh_fast(s4[0]), v1 = tanh_fast(s4[1]);
      float v2 = tanh_fast(s4[2]), v3 = tanh_fast(s4[3]);
      uint2 o; o.x = cvtpk(v0, v1); o.y = cvtpk(v2, v3);
      st8_coh(hb + (size_t)((s + 1) & 7) * BH + (size_t)gr * H_ + gc, o);
      asm volatile("s_waitcnt vmcnt(0)" ::: "memory");   // store drained
      __syncthreads();
      if (tid == 0)
        __hip_atomic_store(flags + bid * 16, s + 1, __ATOMIC_RELAXED, __HIP_MEMORY_SCOPE_AGENT);
      // no trailing barrier: next iteration's x-part is independent; its poll
      // (with its own __syncthreads) provides the ordering.
    } else {
      f32x4 o;
      o[0] = tanh_fast(s4[0]); o[1] = tanh_fast(s4[1]);
      o[2] = tanh_fast(s4[2]); o[3] = tanh_fast(s4[3]);
      *(f32x4*)(out + (size_t)gr * H_ + gc)              = o;
      *(f32x4*)(out + (size_t)BH + (size_t)gr * H_ + gc) = o;
    }
  }
}

// ---------------------------------------------------------------------- host
extern "C" void kernel_launch(void* const* d_in, const int* in_sizes, int n_in,
                              void* d_out, int out_size, void* d_ws, size_t ws_size,
                              hipStream_t stream) {
  const float* xs   = (const float*)d_in[0];
  const float* W    = (const float*)d_in[1];
  const float* bias = (const float*)d_in[2];
  float* out = (float*)d_out;
  char*  ws  = (char*)d_ws;

  const size_t HB_OFF = 0;                       // bf16 h x 8 buffers: 4 MiB
  const size_t BR_OFF = HB_OFF + 8 * 524288;     // flags: 16 KiB (host memset)
  const size_t NEED   = BR_OFF + 16384;
  if (ws_size < NEED) {
    hipMemsetAsync(d_out, 0, (size_t)out_size * 4, stream);
    return;
  }

  ushort* hb    = (ushort*)(ws + HB_OFF);
  int*    flags = (int*)(ws + BR_OFF);

  // flags must be fresh every call (ws not re-poisoned between replays)
  hipMemsetAsync(flags, 0, 256 * 16 * sizeof(int), stream);

  rnn_scan<<<256, 256, 0, stream>>>(W, xs, bias, hb, out, flags);
}

// Round 15
// 5157.434 us; speedup vs baseline: 1.0937x; 1.0937x over previous
//
#include <hip/hip_runtime.h>
#include <hip/hip_bf16.h>
#include <stdint.h>

#define B_  256
#define T_  512
#define H_  1024
#define BH  (B_ * H_)

typedef float  f32x4  __attribute__((ext_vector_type(4)));
typedef float  f32x16 __attribute__((ext_vector_type(16)));
typedef __bf16 bf16x8 __attribute__((ext_vector_type(8)));

// packed f32x2 -> bf16x2 (low = a, high = b), RNE in HW
__device__ inline uint32_t cvtpk(float a, float b) {
  uint32_t r;
  asm("v_cvt_pk_bf16_f32 %0, %1, %2" : "=v"(r) : "v"(a), "v"(b));
  return r;
}
__device__ inline bf16x8 as_bf8(uint4 u) {
  union { uint4 a; bf16x8 b; } v; v.a = u; return v.b;
}
// 8 fp32 (two uint4-bitcast float4s) -> bf16x8, order-preserving
__device__ inline bf16x8 cvt8(uint4 lo, uint4 hi) {
  union { uint4 u; float4 v; } a, b;
  a.u = lo; b.u = hi;
  uint4 w;
  w.x = cvtpk(a.v.x, a.v.y); w.y = cvtpk(a.v.z, a.v.w);
  w.z = cvtpk(b.v.x, b.v.y); w.w = cvtpk(b.v.z, b.v.w);
  return as_bf8(w);
}
// plain cached 16B load, UNTRACKED (caller waits vmcnt). h-freshness guaranteed
// by 8-deep buffer rotation + agent-acquire fence every 8 steps (r12/r13-proven).
__device__ inline uint4 ld16_pl(const void* p) {
  uint4 r;
  asm volatile("global_load_dwordx4 %0, %1, off" : "=&v"(r) : "v"(p));
  return r;
}
// device-scope 8B store (to coherence point; visible to all XCDs)
__device__ inline void st8_coh(ushort* p, uint2 v) {
  asm volatile("global_store_dwordx2 %0, %1, off sc1" :: "v"(p), "v"(v) : "memory");
}
__device__ inline float tanh_fast(float x) {
  float xc = fminf(fmaxf(x, -15.f), 15.f);
  float e  = __expf(2.f * xc);
  return (e - 1.f) * __builtin_amdgcn_rcpf(e + 1.f);
}

// ------------------------------------------- fused persistent RNN (x + scan)
// r14 fusion, rescheduled so the x-part is OFF the critical chain:
//   end of iter s-1: store h(s) -> issue XF batch0 (x chunks 0..15 of step s)
//                    -> vmcnt(16) drains store only -> flag post
//   loop top s:      vmcnt(0) [batch0 ready] -> x-MFMA 0..7 -> issue batch1
//                    (SAME XF regs) -> poll h(s) [batch1 flies during poll]
//                    -> h-loads -> vmcnt(8) [batch1 + A:0..7 ready] ->
//                    x-MFMA 8..15 + h-MFMA 0..7 -> vmcnt(0) -> h-MFMA 8..15
// XF[16] = 64 VGPRs (r14's XF[32]=128 caused spill). Critical path = poll +
// h-part + reduce + store-drain + flag, as in r13; x-work lives in the slack.
__global__ __launch_bounds__(256) void rnn_scan(const float* __restrict__ W,
                                                const float* __restrict__ xs,
                                                const float* __restrict__ bias,
                                                ushort* __restrict__ hb,
                                                float* __restrict__ out,
                                                int* __restrict__ flags) {
  __shared__ ushort Wxs[32 * 1024];          // 64 KB: Wx cols [ct*32, +32)
  __shared__ ushort Whs[32 * 1024];          // 64 KB: Wh cols [ct*32, +32)
  __shared__ float  Psm[2][32][68];          // 17 KB partials (2-phase reduce)
  const int bid = blockIdx.x, tid = threadIdx.x;
  const int rt = bid & 7, ct = bid >> 3;     // XCD-aligned (r13-proven)
  const int lane = tid & 63;
  const int kq = tid >> 6;                   // wave: K-quarter [kq*256, +256)
  const int l31 = lane & 31, l5 = lane >> 5;
  const int rbase = rt * 32;

  // ---- one-time stage: Wx AND Wh cols -> bf16 LDS, 16B-granule swizzle
  {
    const int c  = tid >> 3;                 // 0..31  (local col)
    const int qb = (tid & 7) * 16;           // 16 x 16B chunks per thread
    const float* srcx = W + (size_t)(ct * 32 + c) * 2048;        // Wx
    const float* srch = srcx + 1024;                             // Wh
    char* dstx = (char*)Wxs + c * 2048;
    char* dsth = (char*)Whs + c * 2048;
    const int sw = (c & 7) << 4;
#pragma unroll
    for (int q = qb; q < qb + 16; ++q) {
      float4 f0 = *(const float4*)(srcx + q * 8);
      float4 f1 = *(const float4*)(srcx + q * 8 + 4);
      uint4 w;
      w.x = cvtpk(f0.x, f0.y); w.y = cvtpk(f0.z, f0.w);
      w.z = cvtpk(f1.x, f1.y); w.w = cvtpk(f1.z, f1.w);
      *(uint4*)(dstx + ((q * 16) ^ sw)) = w;
      f0 = *(const float4*)(srch + q * 8);
      f1 = *(const float4*)(srch + q * 8 + 4);
      w.x = cvtpk(f0.x, f0.y); w.y = cvtpk(f0.z, f0.w);
      w.z = cvtpk(f1.x, f1.y); w.w = cvtpk(f1.z, f1.w);
      *(uint4*)(dsth + ((q * 16) ^ sw)) = w;
    }
  }
  __syncthreads();

  // B frag (r8-proven): col = ct*32 + l31, k = kq*256 + c*16 + l5*8
  const int swz = (l31 & 7) << 4;
  const char* bpx = (char*)Wxs + l31 * 2048 + kq * 512;
  const char* bph = (char*)Whs + l31 * 2048 + kq * 512;
  // C/D rows (m74/m101): row = (r&3) + 8*(r>>2) + 4*l5, col = l31
  int crow[16];
#pragma unroll
  for (int r = 0; r < 16; ++r) crow[r] = (r & 3) + 8 * (r >> 2) + 4 * l5;

  // repack indexing: thread -> (row, 4 cols)
  const int prow = tid >> 3, pcg = tid & 7;
  const int gr = rbase + prow;
  const int gc = ct * 32 + pcg * 4;
  const f32x4 bias4 = *(const f32x4*)(bias + gc);

  // per-wave xs row base (lane's k-slice)
  const float* xbase = xs + (size_t)(rbase + l31) * 512 * 1024 + kq * 256 + l5 * 8;

  // ---- prologue: issue XF batch0 for s = 0
  uint4 XF[16];
#pragma unroll
  for (int c = 0; c < 8; ++c) {
    XF[2 * c]     = ld16_pl(xbase + c * 16);
    XF[2 * c + 1] = ld16_pl(xbase + c * 16 + 4);
  }

  for (int s = 0; s < T_; ++s) {
    const float* xrow = xbase + (size_t)s * 1024;

    // batch0 ready
    asm volatile("s_waitcnt vmcnt(0)" ::: "memory");
    __builtin_amdgcn_sched_barrier(0);

    f32x16 acc;
#pragma unroll
    for (int i = 0; i < 16; ++i) acc[i] = 0.f;

    // x-MFMA 0..7 (consumes batch0)
#pragma unroll
    for (int c = 0; c < 8; ++c) {
      const int off = ((c * 32) | (l5 * 16)) ^ swz;
      acc = __builtin_amdgcn_mfma_f32_32x32x16_bf16(cvt8(XF[2 * c], XF[2 * c + 1]),
                                                    *(const bf16x8*)(bpx + off), acc, 0, 0, 0);
    }
    // issue batch1 (chunks for x-MFMA 8..15) into the SAME registers
#pragma unroll
    for (int c = 0; c < 8; ++c) {
      XF[2 * c]     = ld16_pl(xrow + (c + 8) * 16);
      XF[2 * c + 1] = ld16_pl(xrow + (c + 8) * 16 + 4);
    }

    if (s > 0) {
      // poll h(s) — batch1 x-loads fly during the wait
      if (tid < 32) {
        while (__hip_atomic_load(flags + (tid * 8 + rt) * 16, __ATOMIC_RELAXED,
                                 __HIP_MEMORY_SCOPE_AGENT) < s) {}
      }
      __syncthreads();
      // periodic invalidate before h-reads of a reused buffer generation.
      // (drains vmcnt incl. x-loads — xs is read-only, so harmless)
      if ((s & 7) == 1) __builtin_amdgcn_fence(__ATOMIC_ACQUIRE, "agent");

      const ushort* hprev = hb + (size_t)(s & 7) * BH;
      const ushort* arow  = hprev + (size_t)(rbase + l31) * H_ + kq * 256 + l5 * 8;
      uint4 A[16];
#pragma unroll
      for (int c = 0; c < 16; ++c) A[c] = ld16_pl(arow + c * 16);

      // batch1 (older) fully ready + A chunks 0..7 ready
      asm volatile("s_waitcnt vmcnt(8)" ::: "memory");
      __builtin_amdgcn_sched_barrier(0);
#pragma unroll
      for (int c = 8; c < 16; ++c) {
        const int off = ((c * 32) | (l5 * 16)) ^ swz;
        acc = __builtin_amdgcn_mfma_f32_32x32x16_bf16(cvt8(XF[2 * (c - 8)], XF[2 * (c - 8) + 1]),
                                                      *(const bf16x8*)(bpx + off), acc, 0, 0, 0);
      }
#pragma unroll
      for (int c = 0; c < 8; ++c) {
        const int off = ((c * 32) | (l5 * 16)) ^ swz;
        acc = __builtin_amdgcn_mfma_f32_32x32x16_bf16(as_bf8(A[c]),
                                                      *(const bf16x8*)(bph + off), acc, 0, 0, 0);
      }
      asm volatile("s_waitcnt vmcnt(0)" ::: "memory");
      __builtin_amdgcn_sched_barrier(0);
#pragma unroll
      for (int c = 8; c < 16; ++c) {
        const int off = ((c * 32) | (l5 * 16)) ^ swz;
        acc = __builtin_amdgcn_mfma_f32_32x32x16_bf16(as_bf8(A[c]),
                                                      *(const bf16x8*)(bph + off), acc, 0, 0, 0);
      }
    } else {
      // s == 0: h0 == 0 — just finish the x-part
      asm volatile("s_waitcnt vmcnt(0)" ::: "memory");
      __builtin_amdgcn_sched_barrier(0);
#pragma unroll
      for (int c = 8; c < 16; ++c) {
        const int off = ((c * 32) | (l5 * 16)) ^ swz;
        acc = __builtin_amdgcn_mfma_f32_32x32x16_bf16(cvt8(XF[2 * (c - 8)], XF[2 * (c - 8) + 1]),
                                                      *(const bf16x8*)(bpx + off), acc, 0, 0, 0);
      }
    }

    // ---- 2-phase deterministic K-reduce through Psm
    if (kq < 2) {
#pragma unroll
      for (int r = 0; r < 16; ++r) Psm[kq][crow[r]][l31] = acc[r];
    }
    __syncthreads();
    if (kq >= 2) {
#pragma unroll
      for (int r = 0; r < 16; ++r) Psm[kq - 2][crow[r]][l31] += acc[r];
    }
    __syncthreads();

    f32x4 s4 = *(const f32x4*)&Psm[0][prow][pcg * 4]
             + *(const f32x4*)&Psm[1][prow][pcg * 4] + bias4;

    if (s < T_ - 1) {
      float v0 = tanh_fast(s4[0]), v1 = tanh_fast(s4[1]);
      float v2 = tanh_fast(s4[2]), v3 = tanh_fast(s4[3]);
      uint2 o; o.x = cvtpk(v0, v1); o.y = cvtpk(v2, v3);
      st8_coh(hb + (size_t)((s + 1) & 7) * BH + (size_t)gr * H_ + gc, o);
      // issue XF batch0 for step s+1 — AFTER the store, so vmcnt(16) drains
      // exactly the store while the 16 x-loads keep flying under the barrier
      const float* xnext = xbase + (size_t)(s + 1) * 1024;
#pragma unroll
      for (int c = 0; c < 8; ++c) {
        XF[2 * c]     = ld16_pl(xnext + c * 16);
        XF[2 * c + 1] = ld16_pl(xnext + c * 16 + 4);
      }
      asm volatile("s_waitcnt vmcnt(16)" ::: "memory");  // store retired
      __syncthreads();
      if (tid == 0)
        __hip_atomic_store(flags + bid * 16, s + 1, __ATOMIC_RELAXED, __HIP_MEMORY_SCOPE_AGENT);
      // no trailing barrier: next iteration's poll (with its own
      // __syncthreads) provides the ordering.
    } else {
      f32x4 o;
      o[0] = tanh_fast(s4[0]); o[1] = tanh_fast(s4[1]);
      o[2] = tanh_fast(s4[2]); o[3] = tanh_fast(s4[3]);
      *(f32x4*)(out + (size_t)gr * H_ + gc)              = o;
      *(f32x4*)(out + (size_t)BH + (size_t)gr * H_ + gc) = o;
    }
  }
}

// ---------------------------------------------------------------------- host
extern "C" void kernel_launch(void* const* d_in, const int* in_sizes, int n_in,
                              void* d_out, int out_size, void* d_ws, size_t ws_size,
                              hipStream_t stream) {
  const float* xs   = (const float*)d_in[0];
  const float* W    = (const float*)d_in[1];
  const float* bias = (const float*)d_in[2];
  float* out = (float*)d_out;
  char*  ws  = (char*)d_ws;

  const size_t HB_OFF = 0;                       // bf16 h x 8 buffers: 4 MiB
  const size_t BR_OFF = HB_OFF + 8 * 524288;     // flags: 16 KiB (host memset)
  const size_t NEED   = BR_OFF + 16384;
  if (ws_size < NEED) {
    hipMemsetAsync(d_out, 0, (size_t)out_size * 4, stream);
    return;
  }

  ushort* hb    = (ushort*)(ws + HB_OFF);
  int*    flags = (int*)(ws + BR_OFF);

  // flags must be fresh every call (ws not re-poisoned between replays)
  hipMemsetAsync(flags, 0, 256 * 16 * sizeof(int), stream);

  rnn_scan<<<256, 256, 0, stream>>>(W, xs, bias, hb, out, flags);
}

// Round 16
// 2955.465 us; speedup vs baseline: 1.9085x; 1.7450x over previous
//
#include <hip/hip_runtime.h>
#include <hip/hip_bf16.h>
#include <stdint.h>

#define B_  256
#define T_  512
#define H_  1024
#define BH  (B_ * H_)

typedef float  f32x4  __attribute__((ext_vector_type(4)));
typedef float  f32x16 __attribute__((ext_vector_type(16)));
typedef __bf16 bf16x8 __attribute__((ext_vector_type(8)));

__device__ inline ushort f2bf(float f) {
  union { float f; uint32_t u; } v; v.f = f;
  uint32_t u = v.u;
  return (ushort)((u + 0x7fffu + ((u >> 16) & 1u)) >> 16);   // RNE
}
__device__ inline float bf2f(ushort h) {
  union { uint32_t u; float f; } v; v.u = ((uint32_t)h) << 16;
  return v.f;
}
// packed f32x2 -> bf16x2 (low = a, high = b), RNE in HW
__device__ inline uint32_t cvtpk(float a, float b) {
  uint32_t r;
  asm("v_cvt_pk_bf16_f32 %0, %1, %2" : "=v"(r) : "v"(a), "v"(b));
  return r;
}
__device__ inline bf16x8 ld_bf8(const ushort* p) {
  union { uint4 u; bf16x8 b; } v;
  v.u = *(const uint4*)p;
  return v.b;
}
__device__ inline bf16x8 as_bf8(uint4 u) {
  union { uint4 a; bf16x8 b; } v; v.a = u; return v.b;
}
// coherent (device-scope, L2-bypass) 16B load, UNTRACKED: caller waits vmcnt.
__device__ inline uint4 ld16_sc1(const ushort* p) {
  uint4 r;
  asm volatile("global_load_dwordx4 %0, %1, off sc1" : "=&v"(r) : "v"(p));
  return r;
}
// plain cached 8B load, untracked (xp prefetch)
__device__ inline uint2 ld8_pf(const ushort* p) {
  uint2 r;
  asm volatile("global_load_dwordx2 %0, %1, off" : "=&v"(r) : "v"(p));
  return r;
}
// device-scope 8B store (to coherence point; visible to all XCDs)
__device__ inline void st8_coh(ushort* p, uint2 v) {
  asm volatile("global_store_dwordx2 %0, %1, off sc1" :: "v"(p), "v"(v) : "memory");
}
__device__ inline float tanh_fast(float x) {
  float xc = fminf(fmaxf(x, -15.f), 15.f);
  float e  = __expf(2.f * xc);
  return (e - 1.f) * __builtin_amdgcn_rcpf(e + 1.f);
}

// ------------------------------------------------- x_proj = xs @ Wx^T + bias
// (r8 version — passed r8-r13). Output bf16 in (T, B, H) layout.
__global__ __launch_bounds__(256) void xproj_gemm(const float* __restrict__ xs,
                                                  const float* __restrict__ W,
                                                  const float* __restrict__ bias,
                                                  ushort* __restrict__ xp) {
  __shared__ ushort As[128 * 32];
  __shared__ ushort Bs[128 * 32];
  const int bid = blockIdx.x;
  const int mt = bid >> 3, nt = bid & 7;
  const int tid = threadIdx.x;
  const int lane = tid & 63, wid = tid >> 6;
  const int wr = wid >> 1, wc = wid & 1;
  const int lr = lane & 15, lq = lane >> 4;

  const int srow = tid >> 1, scol = (tid & 1) * 16;
  const float* ag = xs + (size_t)(mt * 128 + srow) * 1024 + scol;
  const float* bg = W  + (size_t)(nt * 128 + srow) * 2048 + scol;
  ushort* as = As + srow * 32 + scol;
  ushort* bs = Bs + srow * 32 + scol;

  f32x4 acc[4][4];
#pragma unroll
  for (int m = 0; m < 4; ++m)
#pragma unroll
    for (int n = 0; n < 4; ++n) acc[m][n] = (f32x4){0.f, 0.f, 0.f, 0.f};

  for (int kc = 0; kc < 32; ++kc) {
    float4 a0 = *(const float4*)(ag + kc * 32);
    float4 a1 = *(const float4*)(ag + kc * 32 + 4);
    float4 a2 = *(const float4*)(ag + kc * 32 + 8);
    float4 a3 = *(const float4*)(ag + kc * 32 + 12);
    float4 b0 = *(const float4*)(bg + kc * 32);
    float4 b1 = *(const float4*)(bg + kc * 32 + 4);
    float4 b2 = *(const float4*)(bg + kc * 32 + 8);
    float4 b3 = *(const float4*)(bg + kc * 32 + 12);
    __syncthreads();
    {
      uint4 w0, w1;
      w0.x = cvtpk(a0.x, a0.y); w0.y = cvtpk(a0.z, a0.w);
      w0.z = cvtpk(a1.x, a1.y); w0.w = cvtpk(a1.z, a1.w);
      w1.x = cvtpk(a2.x, a2.y); w1.y = cvtpk(a2.z, a2.w);
      w1.z = cvtpk(a3.x, a3.y); w1.w = cvtpk(a3.z, a3.w);
      *(uint4*)as       = w0;
      *(uint4*)(as + 8) = w1;
      w0.x = cvtpk(b0.x, b0.y); w0.y = cvtpk(b0.z, b0.w);
      w0.z = cvtpk(b1.x, b1.y); w0.w = cvtpk(b1.z, b1.w);
      w1.x = cvtpk(b2.x, b2.y); w1.y = cvtpk(b2.z, b2.w);
      w1.z = cvtpk(b3.x, b3.y); w1.w = cvtpk(b3.z, b3.w);
      *(uint4*)bs       = w0;
      *(uint4*)(bs + 8) = w1;
    }
    __syncthreads();
    bf16x8 af[4], bfv[4];
#pragma unroll
    for (int m = 0; m < 4; ++m)
      af[m] = ld_bf8(As + (wr * 64 + m * 16 + lr) * 32 + lq * 8);
#pragma unroll
    for (int n = 0; n < 4; ++n)
      bfv[n] = ld_bf8(Bs + (wc * 64 + n * 16 + lr) * 32 + lq * 8);
#pragma unroll
    for (int m = 0; m < 4; ++m)
#pragma unroll
      for (int n = 0; n < 4; ++n)
        acc[m][n] = __builtin_amdgcn_mfma_f32_16x16x32_bf16(af[m], bfv[n], acc[m][n], 0, 0, 0);
  }

#pragma unroll
  for (int n = 0; n < 4; ++n) {
    int gn = nt * 128 + wc * 64 + n * 16 + lr;
    float bv = bias[gn];
#pragma unroll
    for (int m = 0; m < 4; ++m) {
      int gmb = mt * 128 + wr * 64 + m * 16 + lq * 4;
#pragma unroll
      for (int r = 0; r < 4; ++r) {
        int gm = gmb + r;
        int bi = gm >> 9, ti = gm & 511;     // m = b*512 + t
        xp[((size_t)ti * B_ + bi) * H_ + gn] = f2bf(acc[m][n][r] + bv);
      }
    }
  }
}

// ----------------------------------------------------------- persistent scan
// r11 configuration — best measured (scan 2330 us, total 2944 us). 256 wgs
// (8 rt x 32 ct, rt = bid>>5) x 256 thr. wg = 32 rows x 32 cols; wave =
// K-quarter (256 k) via 32x32x16 MFMA (r8-verified layouts). A-loads: 16
// dwordx4 sc1 per wave, disjoint. Partials via Psm[4] (deterministic).
// Epilogue repacked across all 256 threads: (row, 4 cols)/thread -> ONE sc1
// dwordx2 h-store + ONE dwordx2 xp prefetch. Flag protocol r5-proven.
__global__ __launch_bounds__(256) void rnn_scan(const float* __restrict__ W,
                                                const ushort* __restrict__ xp,
                                                ushort* __restrict__ hb,
                                                float* __restrict__ out,
                                                int* __restrict__ flags) {
  __shared__ ushort Bsm[32 * 1024];          // 64 KB: Wh cols [ct*32, +32)
  __shared__ float  Psm[4][32][68];          // 34 KB K-quarter partials
  const int bid = blockIdx.x, tid = threadIdx.x;
  const int rt = bid >> 5, ct = bid & 31;    // 8 row-tiles x 32 col-tiles
  const int lane = tid & 63;
  const int kq = tid >> 6;                   // wave: K-quarter [kq*256, +256)
  const int l31 = lane & 31, l5 = lane >> 5;
  const int rbase = rt * 32;

  // ---- one-time stage (r5-proven): Wh -> bf16 LDS, 16B-granule swizzle
  {
    const int c  = tid >> 3;                 // 0..31  (local col)
    const int qb = (tid & 7) * 16;           // 16 x 16B chunks per thread
    const float* src = W + (size_t)(ct * 32 + c) * 2048 + 1024;
    char* dst = (char*)Bsm + c * 2048;
    const int sw = (c & 7) << 4;
#pragma unroll
    for (int q = qb; q < qb + 16; ++q) {
      float4 f0 = *(const float4*)(src + q * 8);
      float4 f1 = *(const float4*)(src + q * 8 + 4);
      uint4 w;
      w.x = cvtpk(f0.x, f0.y); w.y = cvtpk(f0.z, f0.w);
      w.z = cvtpk(f1.x, f1.y); w.w = cvtpk(f1.z, f1.w);
      *(uint4*)(dst + ((q * 16) ^ sw)) = w;
    }
  }
  __syncthreads();

  // B frag (r8-proven): col = ct*32 + l31, k = kq*256 + c*16 + l5*8
  const int swz = (l31 & 7) << 4;
  const char* bp = (char*)Bsm + l31 * 2048 + kq * 512;
  // C/D rows (m74/m101): row = (r&3) + 8*(r>>2) + 4*l5, col = l31
  int crow[16];
#pragma unroll
  for (int r = 0; r < 16; ++r) crow[r] = (r & 3) + 8 * (r >> 2) + 4 * l5;

  // repack indexing: thread -> (row, 4 cols)
  const int prow = tid >> 3, pcg = tid & 7;
  const int gr = rbase + prow;
  const int gc = ct * 32 + pcg * 4;

  uint2 xv;                                  // 4 bf16 of next step's xp

  // ---- step 0: h1 = tanh(xp[0])  (h0 == 0); store + prefetch xp[1]
  {
    uint2 x0 = *(const uint2*)(xp + (size_t)gr * H_ + gc);
    const ushort* xu = (const ushort*)&x0;
    float v0 = tanh_fast(bf2f(xu[0])), v1 = tanh_fast(bf2f(xu[1]));
    float v2 = tanh_fast(bf2f(xu[2])), v3 = tanh_fast(bf2f(xu[3]));
    uint2 o; o.x = cvtpk(v0, v1); o.y = cvtpk(v2, v3);
    st8_coh(hb + (size_t)gr * H_ + gc, o);
    xv = ld8_pf(xp + (size_t)BH + (size_t)gr * H_ + gc);
    asm volatile("s_waitcnt vmcnt(1)" ::: "memory");   // store drained
  }
  __syncthreads();
  if (tid == 0)
    __hip_atomic_store(flags + bid * 16, 1, __ATOMIC_RELAXED, __HIP_MEMORY_SCOPE_AGENT);
  if (tid < 32) {
    while (__hip_atomic_load(flags + (rt * 32 + tid) * 16, __ATOMIC_RELAXED,
                             __HIP_MEMORY_SCOPE_AGENT) < 1) {}
  }
  __syncthreads();

  for (int s = 1; s < T_; ++s) {
    const ushort* hprev = hb + ((s + 1) & 1) * BH;
    ushort*       hnext = hb + (s & 1) * BH;
    // A frag (r8-proven): row = rbase + l31, k = kq*256 + c*16 + l5*8
    const ushort* arow = hprev + (size_t)(rbase + l31) * H_ + kq * 256 + l5 * 8;

    // 16 disjoint sc1 A-loads (this wave's K-quarter)
    uint4 A[16];
#pragma unroll
    for (int c = 0; c < 16; ++c) A[c] = ld16_sc1(arow + c * 16);

    asm volatile("s_waitcnt vmcnt(8)" ::: "memory");   // pf + chunks 0..7 ready
    __builtin_amdgcn_sched_barrier(0);

    f32x16 acc;
#pragma unroll
    for (int i = 0; i < 16; ++i) acc[i] = 0.f;

#pragma unroll
    for (int c = 0; c < 8; ++c) {
      const int off = ((c * 32) | (l5 * 16)) ^ swz;
      acc = __builtin_amdgcn_mfma_f32_32x32x16_bf16(as_bf8(A[c]), *(const bf16x8*)(bp + off), acc, 0, 0, 0);
    }
    asm volatile("s_waitcnt vmcnt(0)" ::: "memory");
    __builtin_amdgcn_sched_barrier(0);
#pragma unroll
    for (int c = 8; c < 16; ++c) {
      const int off = ((c * 32) | (l5 * 16)) ^ swz;
      acc = __builtin_amdgcn_mfma_f32_32x32x16_bf16(as_bf8(A[c]), *(const bf16x8*)(bp + off), acc, 0, 0, 0);
    }

    // write this wave's K-quarter partials
#pragma unroll
    for (int r = 0; r < 16; ++r) Psm[kq][crow[r]][l31] = acc[r];
    __syncthreads();

    // repack combine: all 256 threads, (row, 4 cols) each
    f32x4 s4 = *(const f32x4*)&Psm[0][prow][pcg * 4]
             + *(const f32x4*)&Psm[1][prow][pcg * 4]
             + *(const f32x4*)&Psm[2][prow][pcg * 4]
             + *(const f32x4*)&Psm[3][prow][pcg * 4];
    const ushort* xu = (const ushort*)&xv;

    if (s < T_ - 1) {
      float v0 = tanh_fast(s4[0] + bf2f(xu[0])), v1 = tanh_fast(s4[1] + bf2f(xu[1]));
      float v2 = tanh_fast(s4[2] + bf2f(xu[2])), v3 = tanh_fast(s4[3] + bf2f(xu[3]));
      uint2 o; o.x = cvtpk(v0, v1); o.y = cvtpk(v2, v3);
      st8_coh(hnext + (size_t)gr * H_ + gc, o);
      xv = ld8_pf(xp + (size_t)(s + 1) * BH + (size_t)gr * H_ + gc);
      asm volatile("s_waitcnt vmcnt(1)" ::: "memory"); // store drained, pf flying
      __syncthreads();
      if (tid == 0)
        __hip_atomic_store(flags + bid * 16, s + 1, __ATOMIC_RELAXED, __HIP_MEMORY_SCOPE_AGENT);
      if (tid < 32) {
        while (__hip_atomic_load(flags + (rt * 32 + tid) * 16, __ATOMIC_RELAXED,
                                 __HIP_MEMORY_SCOPE_AGENT) < s + 1) {}
      }
      __syncthreads();
    } else {
      f32x4 o;
      o[0] = tanh_fast(s4[0] + bf2f(xu[0])); o[1] = tanh_fast(s4[1] + bf2f(xu[1]));
      o[2] = tanh_fast(s4[2] + bf2f(xu[2])); o[3] = tanh_fast(s4[3] + bf2f(xu[3]));
      *(f32x4*)(out + (size_t)gr * H_ + gc)               = o;
      *(f32x4*)(out + (size_t)BH + (size_t)gr * H_ + gc)  = o;
    }
  }
}

// ---------------------------------------------------------------------- host
extern "C" void kernel_launch(void* const* d_in, const int* in_sizes, int n_in,
                              void* d_out, int out_size, void* d_ws, size_t ws_size,
                              hipStream_t stream) {
  const float* xs   = (const float*)d_in[0];
  const float* W    = (const float*)d_in[1];
  const float* bias = (const float*)d_in[2];
  float* out = (float*)d_out;
  char*  ws  = (char*)d_ws;

  const size_t XP_OFF = 0;                       // bf16 x_proj (T,B,H): 256 MiB
  const size_t HB_OFF = 268435456;               // bf16 h double-buffer: 1 MiB
  const size_t BR_OFF = HB_OFF + 1048576;        // flags: 16 KiB (host memset)
  const size_t NEED   = BR_OFF + 16384;
  if (ws_size < NEED) {
    hipMemsetAsync(d_out, 0, (size_t)out_size * 4, stream);
    return;
  }

  ushort* xp    = (ushort*)(ws + XP_OFF);
  ushort* hb    = (ushort*)(ws + HB_OFF);
  int*    flags = (int*)(ws + BR_OFF);

  // flags must be fresh every call (ws not re-poisoned between replays)
  hipMemsetAsync(flags, 0, 256 * 16 * sizeof(int), stream);

  xproj_gemm<<<8192, 256, 0, stream>>>(xs, W, bias, xp);
  rnn_scan<<<256, 256, 0, stream>>>(W, xp, hb, out, flags);
}